// Round 13
// baseline (391.921 us; speedup 1.0000x reference)
//
#include <hip/hip_runtime.h>

// MOGCN on MI355X. Pipeline (R20 = R19 + pipelined gemm_h staging; 7 dispatches):
//  k_prep     : ONE launch, 4 regions (build_wb main / wave-parallel W@a dots /
//               xconv / bitpack). R19: -40us vs separate launches + serial dots.
//  k_boolmm   : launch 1: adj^2 = adj*adj; launch 2: adj^3 = adj * adj^2
//               (sparse-A OR-gather, R16 associativity trick, ~10x work cut).
//  k_gemm_h   : R20: BK=32 single-barrier PIPELINED staging (R8/R13-proven
//               pattern: seed; barrier; stage k+1 into other buffer; compute k).
//               Old form exposed staging latency per K-step (2 barriers, 1 buffer).
//               Halved K-tile keeps dbuf at the SAME 33.8KB LDS -> occupancy
//               unchanged 4 blk/CU (avoids m132-style LDS cliff). K-accum order
//               bit-identical (it=ks64*2+ks32 -> same 32-k windows in order).
//  k_rowl     : exp-free softmax denominators (factorized sums), grid 4608.
//  k_attgemm  : R13 FINAL (126.9us, 0 conflicts, ~85% of LDS-port roofline):
//               exp-free 7-op P-gen, R8 loop structure, unpadded Bts. Structure
//               alternatives R9/R10/R11/R15 all measured >= 138us; do not revisit.
//  k_scorecomb: score+combine FUSED (512 blocks x 384 thr; verified R17/R18).
//
// R17 lesson (448.5us): do not merge HETEROGENEOUS kernels.
//
// Workspace map (bytes), total 159,842,304 (~152.4 MiB):
//  [0)            Xs bf16 16,777,216 | Wb bf16 @16,777,216 (2,490,368)  -- dead after k_gemm_h
//  [0)            H32 fp32 50,331,648 (reuses region above; fully written by k_attgemm)
//  [50,331,648)   hsw bf16 75,497,472   [9][16][128][256][8]
//  [125,829,120)  mbA u64 lvl0 6,291,456 (adj bits; read by BOTH boolmm launches);
//                 dead after boolmm-2 -> rowR1/rowR2/rowRT/rowZr (4 x 589,824 B at
//                 +0/+589,824/+1,179,648/+1,769,472; lvl1 adj^2 at +6,291,456)
//  [138,412,032)  mbT u64 18,874,368    [9][16][16w][1024i]
//  [157,286,400)  fbuf fp32 1,179,648   [2][9][16384]; wh=0 slot = f1L (log2e-scaled)
//  [158,466,048)  G1 fp32 589,824 | [159,055,872) G2 fp32 589,824

typedef unsigned long long u64;
typedef __attribute__((ext_vector_type(4))) float f32x4;
typedef __attribute__((ext_vector_type(8))) short bf16x8;

#define NEGF (-9.0e15f)
#define L2E 1.44269504f

__device__ __forceinline__ float fexp2(float x){
#if __has_builtin(__builtin_amdgcn_exp2f)
  return __builtin_amdgcn_exp2f(x);
#else
  return exp2f(x);
#endif
}
__device__ __forceinline__ float frcp(float x){
#if __has_builtin(__builtin_amdgcn_rcpf)
  return __builtin_amdgcn_rcpf(x);
#else
  return 1.0f/x;
#endif
}
__device__ __forceinline__ unsigned short f2bf(float x){   // RNE
  union { float f; unsigned u; } a; a.f = x;
  unsigned r = a.u + 0x7FFFu + ((a.u >> 16) & 1u);
  return (unsigned short)(r >> 16);
}
__device__ __forceinline__ unsigned pack_bf16x2(float lo, float hi){ // fast round
  union { float f; unsigned u; } a, b; a.f = lo; b.f = hi;
  unsigned ul = a.u + 0x8000u, uh = b.u + 0x8000u;
#if __has_builtin(__builtin_amdgcn_perm)
  return __builtin_amdgcn_perm(uh, ul, 0x07060302u);
#else
  return (ul >> 16) | (uh & 0xFFFF0000u);
#endif
}
__device__ __forceinline__ float tanh_fast(float x){
  float e = fexp2(x * 2.885390082f);  // exp(2x)
  return 1.0f - 2.0f*frcp(e + 1.0f);
}
__device__ __forceinline__ void async_cp16(void* lds, const void* g){
  __builtin_amdgcn_global_load_lds(
      (const __attribute__((address_space(1))) unsigned int*)g,
      (__attribute__((address_space(3))) unsigned int*)lds, 16, 0, 0);
}

// ---------------- merged prep (homogeneous: no LDS, 256 thr, light VGPR) --------

__global__ __launch_bounds__(256) void k_prep(
    const float* __restrict__ W, const float* __restrict__ a1,
    const float* __restrict__ a2, unsigned short* __restrict__ Wb,
    const float* __restrict__ X, unsigned short* __restrict__ Xs,
    const float* __restrict__ adj, u64* __restrict__ mbA0, u64* __restrict__ mbT)
{
  if (blockIdx.x < 608) {
    // ---- build_wb main: transpose W -> bf16 k-swizzled; dot cols done elsewhere
    int idx = blockIdx.x*256 + threadIdx.x;           // g*2432 + c
    if (idx >= 64*2432) return;
    int c = idx % 2432, g = idx / 2432;
    unsigned short o[8];
    if (c < 2304) {
      int s = c >> 8, f = c & 255, t = s % 3, klq = s / 3;   // s = kl*3 + t
      const float* wp = W + ((size_t)(t*3 + klq)*512)*256 + f;
#pragma unroll
      for (int e = 0; e < 8; ++e) o[e] = f2bf(wp[(size_t)(g*8 + e)*256]);
    } else if (c < 2322) {
      return;                                   // dot region writes these
    } else {
#pragma unroll
      for (int e = 0; e < 8; ++e) o[e] = 0;
    }
    ushort4 lo, hi;
    lo.x=o[0]; lo.y=o[1]; lo.z=o[2]; lo.w=o[3];
    hi.x=o[4]; hi.y=o[5]; hi.z=o[6]; hi.w=o[7];
    ushort4* dst = (ushort4*)(Wb + (size_t)idx*8);
    dst[0] = lo; dst[1] = hi;
  } else if (blockIdx.x < 896) {
    // ---- W@a1 / W@a2 dot columns, wave-parallel: wave = (c2,g), 8 dots of 256
    int wv = (blockIdx.x - 608)*4 + (threadIdx.x >> 6);   // 1152 waves = 18*64
    int lane = threadIdx.x & 63;
    int c2 = wv >> 6, g = wv & 63;
    int s = c2 >> 1, t = s % 3, klq = s / 3;
    const float* av = ((c2 & 1) ? a2 : a1) + (t*3 + klq)*256;
    const float* wp = W + ((size_t)(t*3 + klq)*512)*256;
    float4 avv = *(const float4*)(av + lane*4);
    unsigned short o[8];
#pragma unroll
    for (int e = 0; e < 8; ++e) {
      float4 wv4 = *(const float4*)(wp + (size_t)(g*8 + e)*256 + lane*4);
      float p = wv4.x*avv.x + wv4.y*avv.y + wv4.z*avv.z + wv4.w*avv.w;
#pragma unroll
      for (int off = 32; off; off >>= 1) p += __shfl_xor(p, off);
      o[e] = f2bf(p);
    }
    if (lane == 0) {
      ushort4 lo, hi;
      lo.x=o[0]; lo.y=o[1]; lo.z=o[2]; lo.w=o[3];
      hi.x=o[4]; hi.y=o[5]; hi.z=o[6]; hi.w=o[7];
      ushort4* dst = (ushort4*)(Wb + (size_t)(g*2432 + 2304 + c2)*8);
      dst[0] = lo; dst[1] = hi;
    }
  } else if (blockIdx.x < 4992) {
    // ---- xconv ----
    int idx = (blockIdx.x - 896)*256 + threadIdx.x;   // g*16384 + bn
    int bn = idx & 16383, g = idx >> 14;
    const float* xp = X + (size_t)bn*512 + g*8;
    ushort4 lo, hi;
    lo.x=f2bf(xp[0]); lo.y=f2bf(xp[1]); lo.z=f2bf(xp[2]); lo.w=f2bf(xp[3]);
    hi.x=f2bf(xp[4]); hi.y=f2bf(xp[5]); hi.z=f2bf(xp[6]); hi.w=f2bf(xp[7]);
    ushort4* dst = (ushort4*)(Xs + (size_t)idx*8);
    dst[0] = lo; dst[1] = hi;
  } else {
    // ---- bitpack (wave-per-row, 2 rows/wave) ----
    int gw = (blockIdx.x - 4992)*4 + (threadIdx.x >> 6);
    int lane = threadIdx.x & 63;
#pragma unroll
    for (int r = 0; r < 2; ++r) {
      int row = gw*2 + r;                  // bt*1024 + i, bt = b*3 + t
      int i = row & 1023, bt = row >> 10;
      int t = bt % 3, b = bt / 3;
      int sb = t*16 + b;
      const float* ap = adj + (size_t)row*1024 + lane;
      u64 myw = 0;
#pragma unroll
      for (int w = 0; w < 16; ++w) {
        u64 bal = __ballot(ap[w*64] > 0.0f);
        if (lane == w) myw = bal;
      }
      if (lane < 16) {
        mbA0[((size_t)sb*1024 + i)*16 + lane] = myw;
        mbT[((size_t)sb*16 + lane)*1024 + i] = myw;
      }
    }
  }
}

__global__ void k_boolmm(const u64* __restrict__ A, const u64* __restrict__ Bm,
                         u64* __restrict__ outA, u64* __restrict__ outT, int sbase)
{
  int tid = blockIdx.x*256 + threadIdx.x;   // 48*1024*16
  int w = tid & 15, i = (tid >> 4) & 1023, tb = tid >> 14;
  const u64* Ar = A + ((size_t)tb*1024 + i)*16;
  const u64* Bb = Bm + (size_t)tb*16384;
  u64 acc = 0;
  for (int ww = 0; ww < 16; ++ww) {
    u64 aw = Ar[ww];
    while (aw) {
      int kk = __builtin_ctzll(aw);
      aw &= aw - 1;
      acc |= Bb[((size_t)(ww*64 + kk))*16 + w];
    }
  }
  if (outA) outA[((size_t)tb*1024 + i)*16 + w] = acc;
  int t = tb >> 4, bq = tb & 15;
  outT[(((size_t)(sbase + t)*16 + bq)*16 + w)*1024 + i] = acc;
}

// ---------------- h = X@W GEMM (bf16 MFMA), fused f1L + G1/G2 epilogue -------
// R20: BK=32 pipelined staging. 16 iterations, one barrier each; stage tile it+1
// into buf[(it+1)&1] right after the barrier while computing tile it from buf[it&1].
// Same 33.8KB LDS / 4 blk/CU as the old two-barrier form; bit-identical K order.

__global__ __launch_bounds__(256) void k_gemm_h(
    const unsigned short* __restrict__ Xs, const unsigned short* __restrict__ Wb,
    unsigned short* __restrict__ hsw, float* __restrict__ fbuf,
    float* __restrict__ G1p, float* __restrict__ G2p)
{
  __shared__ unsigned short Asl[2][4*132*8];   // 2 x 4224 shorts = 16896 B
  __shared__ unsigned short Bsl[2][4*132*8];
  const int tid = threadIdx.x, lane = tid & 63, wid = tid >> 6;
  int vb = blockIdx.x;                       // XCD swizzle: same mt -> same XCD
  int xc = vb & 7, mrest = vb >> 3;
  int mt = xc + 8*(mrest/19), nt = mrest % 19;
  const int M0 = mt << 7, N0 = nt << 7;
  const int wr = (wid >> 1) << 6, wc = (wid & 1) << 6;
  const int me = lane & 15, quad = lane >> 4;
  f32x4 acc[4][4] = {};

  // seed: stage k-tile 0 (kbase 0..3) into buffer 0
#pragma unroll
  for (int c = 0; c < 2; ++c) {
    int chunk = wid*2 + c, g = chunk >> 1, hh = chunk & 1;
    int ldsoff = (g*132 + hh*64)*8;
    async_cp16(&Asl[0][ldsoff], Xs + ((size_t)g*16384 + (M0 + hh*64 + lane))*8);
    async_cp16(&Bsl[0][ldsoff], Wb + ((size_t)g*2432 + (N0 + hh*64 + lane))*8);
  }

  for (int it = 0; it < 16; ++it) {
    __syncthreads();                      // buf[it&1] staged loads drained
    if (it + 1 < 16) {                    // stage next k-tile into other buffer
      int nb = (it + 1) & 1;
#pragma unroll
      for (int c = 0; c < 2; ++c) {
        int chunk = wid*2 + c, g = chunk >> 1, hh = chunk & 1;
        int kb = (it + 1)*4 + g;
        int ldsoff = (g*132 + hh*64)*8;
        async_cp16(&Asl[nb][ldsoff], Xs + ((size_t)kb*16384 + (M0 + hh*64 + lane))*8);
        async_cp16(&Bsl[nb][ldsoff], Wb + ((size_t)kb*2432 + (N0 + hh*64 + lane))*8);
      }
    }
    const int cb2 = it & 1;
    bf16x8 afr[4], bfr[4];
#pragma unroll
    for (int rb = 0; rb < 4; ++rb)
      afr[rb] = *(const bf16x8*)(&Asl[cb2][(quad*132 + wr + rb*16 + me)*8]);
#pragma unroll
    for (int cb = 0; cb < 4; ++cb)
      bfr[cb] = *(const bf16x8*)(&Bsl[cb2][(quad*132 + wc + cb*16 + me)*8]);
#pragma unroll
    for (int rb = 0; rb < 4; ++rb)
#pragma unroll
      for (int cb = 0; cb < 4; ++cb)
        acc[rb][cb] = __builtin_amdgcn_mfma_f32_16x16x32_bf16(afr[rb], bfr[cb], acc[rb][cb], 0, 0, 0);
  }

#pragma unroll
  for (int rb = 0; rb < 4; ++rb) {
    int jbase = M0 + wr + rb*16 + quad*4;
    int bidx = jbase >> 10, jn = jbase & 1023;
#pragma unroll
    for (int cb = 0; cb < 4; ++cb) {
      int c = N0 + wc + cb*16 + me;
      f32x4 v = acc[rb][cb];
      if (c < 2304) {
        int s = c >> 8, f = c & 255;
        ushort4 pk;
        pk.x = f2bf(v[0]); pk.y = f2bf(v[1]); pk.z = f2bf(v[2]); pk.w = f2bf(v[3]);
        *(ushort4*)(hsw + (size_t)s*4194304 + (size_t)bidx*262144 + ((jn>>3)*256 + f)*8 + (jn&7)) = pk;
      } else if (c < 2322) {
        int c2 = c - 2304, s = c2 >> 1, wh = c2 & 1;
        f32x4 vL = v * L2E;                       // log2 domain
        if (wh == 0) {
          *(f32x4*)(fbuf + (size_t)s*16384 + jbase) = vL;   // f1L
        } else {
          f32x4 g1v, g2v;
#pragma unroll
          for (int k = 0; k < 4; ++k) {
            g1v[k] = fexp2(vL[k]);
            g2v[k] = fexp2(0.2f*vL[k]);
          }
          *(f32x4*)(G1p + (size_t)s*16384 + jbase) = g1v;
          *(f32x4*)(G2p + (size_t)s*16384 + jbase) = g2v;
        }
      }
    }
  }
}

// ---------------- per-row softmax denominators (exp-free, factorized) ----------
// Grid-stride, 8 rows per wave (grid 4608 x 256 = 18432 waves; 147456 rows).

__global__ __launch_bounds__(256) void k_rowl(
    const u64* __restrict__ mbT, const float* __restrict__ fbuf,
    const float* __restrict__ G1p, const float* __restrict__ G2p,
    float* __restrict__ rowR1, float* __restrict__ rowR2,
    float* __restrict__ rowRT, float* __restrict__ rowZr)
{
  int lane = threadIdx.x & 63;
  for (int gw = blockIdx.x*4 + (threadIdx.x >> 6); gw < 147456; gw += 18432) {
    int i = gw & 1023, sb = gw >> 10;
    int b = sb & 15, s = sb >> 4;

    const float* g1q = G1p + (size_t)s*16384 + b*1024 + lane*16;
    const float* g2q = G2p + (size_t)s*16384 + b*1024 + lane*16;
    float4 a0 = *(const float4*)(g1q);
    float4 a1 = *(const float4*)(g1q + 4);
    float4 a2 = *(const float4*)(g1q + 8);
    float4 a3 = *(const float4*)(g1q + 12);
    float4 c0 = *(const float4*)(g2q);
    float4 c1 = *(const float4*)(g2q + 4);
    float4 c2 = *(const float4*)(g2q + 8);
    float4 c3 = *(const float4*)(g2q + 12);
    float g1e[16] = {a0.x,a0.y,a0.z,a0.w, a1.x,a1.y,a1.z,a1.w,
                     a2.x,a2.y,a2.z,a2.w, a3.x,a3.y,a3.z,a3.w};
    float g2e[16] = {c0.x,c0.y,c0.z,c0.w, c1.x,c1.y,c1.z,c1.w,
                     c2.x,c2.y,c2.z,c2.w, c3.x,c3.y,c3.z,c3.w};

    u64 word = mbT[(size_t)sb*16384 + (size_t)(lane >> 2)*1024 + i];
    unsigned fld = (unsigned)(word >> ((lane & 3)*16)) & 0xFFFFu;   // 16 mask bits

    float f1i = fbuf[(size_t)s*16384 + b*1024 + i];
    float RT = fexp2(-f1i);

    float S1 = 0.0f, S2 = 0.0f;
#pragma unroll
    for (int e = 0; e < 16; ++e) {
      unsigned m32 = (unsigned)(((int)(fld << (31 - e))) >> 31);   // 0 or ~0
      float t1 = __uint_as_float(__float_as_uint(g1e[e]) & m32);
      float t2 = __uint_as_float(__float_as_uint(g2e[e]) & m32);
      bool c = (g1e[e] >= RT);
      S1 += c ? t1 : 0.0f;
      S2 += c ? 0.0f : t2;
    }
#pragma unroll
    for (int off = 32; off; off >>= 1) {
      S1 += __shfl_xor(S1, off);
      S2 += __shfl_xor(S2, off);
    }
    if (lane == 0) {
      float EF1 = fexp2(f1i);
      float EF2 = fexp2(0.2f*f1i);
      float l = __builtin_fmaf(EF1, S1, EF2*S2);
      float rinv = frcp(l);                 // inf when l==0 (empty row) -- harmless
      rowR1[gw] = EF1*rinv;
      rowR2[gw] = EF2*rinv;
      rowRT[gw] = RT;
      rowZr[gw] = (l == 0.0f) ? 0.0009765625f : 0.0f;   // 2^-10
    }
  }
}

// ---------------- fused attention GEMM: H = sum_t softmax(mask_t(e_t)) @ h_t --------
// R13 FINAL: exp-free 7-op P-gen, R8 loop structure, unpadded Bts (0 conflicts).

__global__ __launch_bounds__(256, 3) void k_attgemm(
    const unsigned short* __restrict__ hsw,
    const float* __restrict__ G1p, const float* __restrict__ G2p,
    const float* __restrict__ rowR1, const float* __restrict__ rowR2,
    const float* __restrict__ rowRT, const float* __restrict__ rowZr,
    const u64* __restrict__ mbT, float* __restrict__ H32)
{
  __shared__ unsigned short Bts[2*8192];      // 2 half-buffers, 16384B each (unpadded)
  const int tid = threadIdx.x, lane = tid & 63, wid = tid >> 6;
  const int me = lane & 15, quad = lane >> 4;
  int vb = blockIdx.x;
  int mt = vb / 48, g = vb % 48;              // g%8 constant across a group's 16 blocks
  int kl = g >> 4, b = g & 15;
  const int i0w = mt*64 + wid*16;
  const int ir0 = i0w + me;
  const unsigned short* hbase = hsw + (size_t)(kl*3)*4194304 + (size_t)b*262144;
  const float* g1b = G1p + (size_t)(kl*3)*16384 + b*1024;
  const float* g2b = G2p + (size_t)(kl*3)*16384 + b*1024;
  const float* R1b = rowR1 + ((kl*3)*16 + b)*1024;
  const float* R2b = rowR2 + ((kl*3)*16 + b)*1024;
  const float* RTb = rowRT + ((kl*3)*16 + b)*1024;
  const float* Zrb = rowZr + ((kl*3)*16 + b)*1024;
  const u64* mb = mbT + (size_t)((kl*3)*16 + b)*16384;   // t-stride 262144 u64

  float R1v, R2v, RTv;
  unsigned Zru;
  f32x4 acc[16] = {};

  // seed: stage iter 0 (t=0, st=0, ks=0) into buffer 0
  {
    const unsigned short* hstage = hbase + wid*2048;
    unsigned short* lb = Bts + wid*2048;
#pragma unroll
    for (int c = 0; c < 4; ++c)
      async_cp16(lb + c*512, hstage + c*512 + lane*8);
  }
  u64 mw = mb[ir0];
  u64 nm = 0;

  for (int it = 0; it < 96; ++it) {
    const int tt = it >> 5, kk = it & 1;
    const int st = (it >> 1) & 15;
    if ((it & 31) == 0) {                 // t boundary: per-row constants for this t
      R1v = R1b[tt*16384 + ir0];
      R2v = R2b[tt*16384 + ir0];
      RTv = RTb[tt*16384 + ir0];
      Zru = __float_as_uint(Zrb[tt*16384 + ir0]);
    }
    if (!kk && it) mw = nm;               // adopt prefetched mask

    __syncthreads();   // drains vmcnt: current half's loads issued one compute ago

    if (it + 1 < 96) {                    // stage next half into other buffer
      int nx = it + 1;
      int nt2 = nx >> 5, ns = (nx >> 1) & 15, nk = nx & 1;
      const unsigned short* hstage = hbase + (size_t)nt2*4194304 + ns*16384 + (nk*4 + wid)*2048;
      unsigned short* lb = Bts + nk*8192 + wid*2048;
#pragma unroll
      for (int c = 0; c < 4; ++c)
        async_cp16(lb + c*512, hstage + c*512 + lane*8);
    }
    if (kk && it + 1 < 96) {              // prefetch mask for next (t,st)
      int gid = (it + 1) >> 1;
      int nt2 = gid >> 4, ns = gid & 15;
      nm = mb[(size_t)nt2*262144 + ns*1024 + ir0];
    }

    // G1/G2 for this 32-k chunk (uniform-per-quad addresses -> L1 broadcast)
    const int joff = tt*16384 + st*64 + kk*32 + quad*8;
    float4 ga = *(const float4*)(g1b + joff);
    float4 gb4 = *(const float4*)(g1b + joff + 4);
    float4 ha = *(const float4*)(g2b + joff);
    float4 hb4 = *(const float4*)(g2b + joff + 4);
    float g1e[8] = {ga.x, ga.y, ga.z, ga.w, gb4.x, gb4.y, gb4.z, gb4.w};
    float g2e[8] = {ha.x, ha.y, ha.z, ha.w, hb4.x, hb4.y, hb4.z, hb4.w};

    const int kloc = kk*32 + quad*8;
    unsigned mby = (unsigned)((mw >> kloc) & 0xFFull);
    union { bf16x8 v; unsigned u[4]; } ua;
#pragma unroll
    for (int p = 0; p < 4; ++p) {
      float p0, p1;
      {
        const int e = 2*p;
        bool c = (g1e[e] >= RTv);
        float pu = (c ? g1e[e] : g2e[e]) * (c ? R1v : R2v);
        unsigned m32 = (unsigned)(((int)(mby << (31 - e))) >> 31);
        p0 = __uint_as_float((__float_as_uint(pu) & m32) | Zru);
      }
      {
        const int e = 2*p + 1;
        bool c = (g1e[e] >= RTv);
        float pu = (c ? g1e[e] : g2e[e]) * (c ? R1v : R2v);
        unsigned m32 = (unsigned)(((int)(mby << (31 - e))) >> 31);
        p1 = __uint_as_float((__float_as_uint(pu) & m32) | Zru);
      }
      ua.u[p] = pack_bf16x2(p0, p1);
    }
    const unsigned short* bbase = Bts + kk*8192 + quad*2048;
#pragma unroll
    for (int cb = 0; cb < 16; ++cb) {
      bf16x8 bf = *(const bf16x8*)(bbase + (cb*16 + me)*8);
      acc[cb] = __builtin_amdgcn_mfma_f32_16x16x32_bf16(ua.v, bf, acc[cb], 0, 0, 0);
    }
  }

  // epilogue: plain stores (each (kl,b,row,f) written exactly once)
  {
    int io = i0w + quad*4;
#pragma unroll
    for (int cb = 0; cb < 16; ++cb) {
      int f = cb*16 + me;
      float* hp = H32 + (((size_t)b*1024 + io)*3 + kl)*256 + f;
#pragma unroll
      for (int r = 0; r < 4; ++r)
        hp[(size_t)r*768] = acc[cb][r];
    }
  }
}

// ---------------- fused layer attention + combine (verified R17/R18) ----------------
// 512 blocks x 384 thr (6 waves). Score phase: rows [blk*96, +96) (= 32 bn x 3 kl),
// s = tanh(H@Ww+bw)@Wc -> svL in LDS. Barrier. Combine phase: softmax over the 3
// layer scores per bn, weighted sum of H32 rows (L2-hot re-read), write out.

__global__ __launch_bounds__(384) void k_scorecomb(
    const float* __restrict__ H32, const float* __restrict__ Ww,
    const float* __restrict__ bwv, const float* __restrict__ Wcv,
    float* __restrict__ out)
{
  __shared__ unsigned short Bs[8*7*64*8];   // 57344 B
  __shared__ float bwL[128], WcL[128];
  __shared__ float svL[96];
  const int tid = threadIdx.x, lane = tid & 63, wid = tid >> 6;   // wid 0..5
  const int me = lane & 15, quad = lane >> 4;
  for (int idx = tid; idx < 3584; idx += 384) {
    int kk = idx / 448, rem = idx % 448;
    int cb = rem >> 6, l = rem & 63;
    int n = cb*16 + (l & 15);
    int kbase = kk*32 + (l >> 4)*8;
    ushort4 lo, hi;
    if (n < 100) {
      const float* wp = Ww + (size_t)kbase*100 + n;
      lo.x = f2bf(wp[0]);   lo.y = f2bf(wp[100]); lo.z = f2bf(wp[200]); lo.w = f2bf(wp[300]);
      hi.x = f2bf(wp[400]); hi.y = f2bf(wp[500]); hi.z = f2bf(wp[600]); hi.w = f2bf(wp[700]);
    } else {
      lo.x=lo.y=lo.z=lo.w=0; hi.x=hi.y=hi.z=hi.w=0;
    }
    ushort4* dst = (ushort4*)(Bs + (size_t)idx*8);
    dst[0] = lo; dst[1] = hi;
  }
  if (tid < 128) {
    bwL[tid] = (tid < 100) ? bwv[tid] : 0.0f;
    WcL[tid] = (tid < 100) ? Wcv[tid] : 0.0f;
  }
  __syncthreads();

  // ---- score phase: 96 rows (rows are (bn*3 + kl) indices into H32) ----
  const int row0 = blockIdx.x*96 + wid*16;
  const float* Arow = H32 + (size_t)(row0 + me)*256;
  f32x4 acc[7] = {};
#pragma unroll
  for (int kk = 0; kk < 8; ++kk) {
    const float* ap = Arow + kk*32 + quad*8;
    float4 a0 = *(const float4*)(ap);
    float4 a1 = *(const float4*)(ap + 4);
    union { bf16x8 v; unsigned u[4]; } ua;
    ua.u[0] = pack_bf16x2(a0.x, a0.y);
    ua.u[1] = pack_bf16x2(a0.z, a0.w);
    ua.u[2] = pack_bf16x2(a1.x, a1.y);
    ua.u[3] = pack_bf16x2(a1.z, a1.w);
#pragma unroll
    for (int cb = 0; cb < 7; ++cb) {
      bf16x8 bf = *(const bf16x8*)(Bs + ((size_t)(kk*7 + cb)*64 + lane)*8);
      acc[cb] = __builtin_amdgcn_mfma_f32_16x16x32_bf16(ua.v, bf, acc[cb], 0, 0, 0);
    }
  }
#pragma unroll
  for (int r = 0; r < 4; ++r) {
    float contrib = 0.0f;
#pragma unroll
    for (int cb = 0; cb < 7; ++cb) {
      int col = cb*16 + me;
      contrib += tanh_fast(acc[cb][r] + bwL[col]) * WcL[col];
    }
    contrib += __shfl_xor(contrib, 1);
    contrib += __shfl_xor(contrib, 2);
    contrib += __shfl_xor(contrib, 4);
    contrib += __shfl_xor(contrib, 8);
    if (me == 0) svL[wid*16 + quad*4 + r] = contrib;
  }
  __syncthreads();

  // ---- combine phase: 32 bn, H32 rows re-read (L2-hot) ----
  const int bn0 = blockIdx.x*32;
  for (int idx = tid; idx < 2048; idx += 384) {
    int fq = idx & 63, bl = idx >> 6;       // bl in [0,32)
    int bn = bn0 + bl;
    float s0 = svL[bl*3], s1 = svL[bl*3+1], s2 = svL[bl*3+2];
    float mm = fmaxf(s0, fmaxf(s1, s2));
    float e0 = fexp2((s0-mm)*L2E), e1 = fexp2((s1-mm)*L2E), e2 = fexp2((s2-mm)*L2E);
    float inv = frcp(e0 + e1 + e2);
    const f32x4* h0 = (const f32x4*)(H32 + (size_t)bn*768) + fq;
    const f32x4* h1 = (const f32x4*)(H32 + (size_t)bn*768 + 256) + fq;
    const f32x4* h2 = (const f32x4*)(H32 + (size_t)bn*768 + 512) + fq;
    f32x4 r = (e0*(*h0) + e1*(*h1) + e2*(*h2))*inv;
    *((f32x4*)out + (size_t)bn*64 + fq) = r;
  }
}

// ---------------- launcher ----------------

extern "C" void kernel_launch(void* const* d_in, const int* in_sizes, int n_in,
                              void* d_out, int out_size, void* d_ws, size_t ws_size,
                              hipStream_t stream) {
  const float* adj = (const float*)d_in[0];
  const float* X   = (const float*)d_in[1];
  const float* W   = (const float*)d_in[2];
  const float* a1  = (const float*)d_in[3];
  const float* a2  = (const float*)d_in[4];
  const float* Ww  = (const float*)d_in[5];
  const float* bw  = (const float*)d_in[6];
  const float* Wc  = (const float*)d_in[7];
  float* out = (float*)d_out;
  char* ws = (char*)d_ws;

  unsigned short* Xs  = (unsigned short*)(ws + 0);
  unsigned short* Wb  = (unsigned short*)(ws + 16777216);
  float* H32          = (float*)(ws + 0);                // reuses Xs/Wb region
  unsigned short* hsw = (unsigned short*)(ws + 50331648);
  u64* mbA            = (u64*)(ws + 125829120);
  float* rowR1        = (float*)(ws + 125829120);        // mbA lvl0, dead after boolmm-2
  float* rowR2        = (float*)(ws + 126418944);
  float* rowRT        = (float*)(ws + 127008768);
  float* rowZr        = (float*)(ws + 127598592);
  u64* mbT            = (u64*)(ws + 138412032);
  float* fbuf         = (float*)(ws + 157286400);        // f1L
  float* G1p          = (float*)(ws + 158466048);
  float* G2p          = (float*)(ws + 159055872);

  // prep: build_wb (parallel dots) | xconv | bitpack -- one homogeneous launch
  k_prep<<<11136, 256, 0, stream>>>(W, a1, a2, Wb, X, Xs, adj, mbA, mbT);
  k_boolmm<<<3072, 256, 0, stream>>>(mbA, mbA, mbA + 786432, mbT, 3);
  // adj^3 = adj * adj^2 (sparse A side: ~10 gathers/word vs ~97 for adj^2 * adj)
  k_boolmm<<<3072, 256, 0, stream>>>(mbA, mbA + 786432, (u64*)nullptr, mbT, 6);
  k_gemm_h<<<2432, 256, 0, stream>>>(Xs, Wb, hsw, fbuf, G1p, G2p);
  k_rowl<<<4608, 256, 0, stream>>>(mbT, fbuf, G1p, G2p, rowR1, rowR2, rowRT, rowZr);
  k_attgemm<<<768, 256, 0, stream>>>(hsw, G1p, G2p, rowR1, rowR2, rowRT, rowZr, mbT, H32);
  k_scorecomb<<<512, 384, 0, stream>>>(H32, Ww, bw, Wc, out);
}

// Round 14
// 383.016 us; speedup vs baseline: 1.0233x; 1.0233x over previous
//
#include <hip/hip_runtime.h>

// MOGCN on MI355X. Pipeline (R21 = R19 exact, the measured-best 383.2us config;
// R20's gemm_h BK=32 pipelining REVERTED: it cost +8.7us -- at 4 blk/CU the
// implicit wave overlap already hides staging, and halving the K-tile halved the
// per-phase ILP window. 7 dispatches):
//  k_prep     : ONE launch, 4 regions (build_wb main / wave-parallel W@a dots /
//               xconv / bitpack). R19: -40us vs separate launches + serial dots.
//  k_boolmm   : launch 1: adj^2 = adj*adj; launch 2: adj^3 = adj * adj^2
//               (sparse-A OR-gather, R16 associativity trick, ~10x work cut).
//  k_gemm_h   : R19 form: BK=64, two barriers per K-step, single buffer.
//  k_rowl     : exp-free softmax denominators (factorized sums), grid 4608.
//  k_attgemm  : R13 FINAL (126.9us, 0 conflicts, ~85% of LDS-port roofline):
//               exp-free 7-op P-gen, R8 loop structure, unpadded Bts. Structure
//               alternatives R9/R10/R11/R15 all measured >= 138us; do not revisit.
//  k_scorecomb: score+combine FUSED (512 blocks x 384 thr; verified R17/R18).
//
// Falsified directions (do not retry without new counters): attgemm structure
// (R9/R10/R11/R15), heterogeneous kernel merge (R17), rowl re-grid (neutral),
// gemm_h explicit pipelining (R20).
//
// Workspace map (bytes), total 159,842,304 (~152.4 MiB):
//  [0)            Xs bf16 16,777,216 | Wb bf16 @16,777,216 (2,490,368)  -- dead after k_gemm_h
//  [0)            H32 fp32 50,331,648 (reuses region above; fully written by k_attgemm)
//  [50,331,648)   hsw bf16 75,497,472   [9][16][128][256][8]
//  [125,829,120)  mbA u64 lvl0 6,291,456 (adj bits; read by BOTH boolmm launches);
//                 dead after boolmm-2 -> rowR1/rowR2/rowRT/rowZr (4 x 589,824 B at
//                 +0/+589,824/+1,179,648/+1,769,472; lvl1 adj^2 at +6,291,456)
//  [138,412,032)  mbT u64 18,874,368    [9][16][16w][1024i]
//  [157,286,400)  fbuf fp32 1,179,648   [2][9][16384]; wh=0 slot = f1L (log2e-scaled)
//  [158,466,048)  G1 fp32 589,824 | [159,055,872) G2 fp32 589,824

typedef unsigned long long u64;
typedef __attribute__((ext_vector_type(4))) float f32x4;
typedef __attribute__((ext_vector_type(8))) short bf16x8;

#define NEGF (-9.0e15f)
#define L2E 1.44269504f

__device__ __forceinline__ float fexp2(float x){
#if __has_builtin(__builtin_amdgcn_exp2f)
  return __builtin_amdgcn_exp2f(x);
#else
  return exp2f(x);
#endif
}
__device__ __forceinline__ float frcp(float x){
#if __has_builtin(__builtin_amdgcn_rcpf)
  return __builtin_amdgcn_rcpf(x);
#else
  return 1.0f/x;
#endif
}
__device__ __forceinline__ unsigned short f2bf(float x){   // RNE
  union { float f; unsigned u; } a; a.f = x;
  unsigned r = a.u + 0x7FFFu + ((a.u >> 16) & 1u);
  return (unsigned short)(r >> 16);
}
__device__ __forceinline__ unsigned pack_bf16x2(float lo, float hi){ // fast round
  union { float f; unsigned u; } a, b; a.f = lo; b.f = hi;
  unsigned ul = a.u + 0x8000u, uh = b.u + 0x8000u;
#if __has_builtin(__builtin_amdgcn_perm)
  return __builtin_amdgcn_perm(uh, ul, 0x07060302u);
#else
  return (ul >> 16) | (uh & 0xFFFF0000u);
#endif
}
__device__ __forceinline__ float tanh_fast(float x){
  float e = fexp2(x * 2.885390082f);  // exp(2x)
  return 1.0f - 2.0f*frcp(e + 1.0f);
}
__device__ __forceinline__ void async_cp16(void* lds, const void* g){
  __builtin_amdgcn_global_load_lds(
      (const __attribute__((address_space(1))) unsigned int*)g,
      (__attribute__((address_space(3))) unsigned int*)lds, 16, 0, 0);
}

// ---------------- merged prep (homogeneous: no LDS, 256 thr, light VGPR) --------

__global__ __launch_bounds__(256) void k_prep(
    const float* __restrict__ W, const float* __restrict__ a1,
    const float* __restrict__ a2, unsigned short* __restrict__ Wb,
    const float* __restrict__ X, unsigned short* __restrict__ Xs,
    const float* __restrict__ adj, u64* __restrict__ mbA0, u64* __restrict__ mbT)
{
  if (blockIdx.x < 608) {
    // ---- build_wb main: transpose W -> bf16 k-swizzled; dot cols done elsewhere
    int idx = blockIdx.x*256 + threadIdx.x;           // g*2432 + c
    if (idx >= 64*2432) return;
    int c = idx % 2432, g = idx / 2432;
    unsigned short o[8];
    if (c < 2304) {
      int s = c >> 8, f = c & 255, t = s % 3, klq = s / 3;   // s = kl*3 + t
      const float* wp = W + ((size_t)(t*3 + klq)*512)*256 + f;
#pragma unroll
      for (int e = 0; e < 8; ++e) o[e] = f2bf(wp[(size_t)(g*8 + e)*256]);
    } else if (c < 2322) {
      return;                                   // dot region writes these
    } else {
#pragma unroll
      for (int e = 0; e < 8; ++e) o[e] = 0;
    }
    ushort4 lo, hi;
    lo.x=o[0]; lo.y=o[1]; lo.z=o[2]; lo.w=o[3];
    hi.x=o[4]; hi.y=o[5]; hi.z=o[6]; hi.w=o[7];
    ushort4* dst = (ushort4*)(Wb + (size_t)idx*8);
    dst[0] = lo; dst[1] = hi;
  } else if (blockIdx.x < 896) {
    // ---- W@a1 / W@a2 dot columns, wave-parallel: wave = (c2,g), 8 dots of 256
    int wv = (blockIdx.x - 608)*4 + (threadIdx.x >> 6);   // 1152 waves = 18*64
    int lane = threadIdx.x & 63;
    int c2 = wv >> 6, g = wv & 63;
    int s = c2 >> 1, t = s % 3, klq = s / 3;
    const float* av = ((c2 & 1) ? a2 : a1) + (t*3 + klq)*256;
    const float* wp = W + ((size_t)(t*3 + klq)*512)*256;
    float4 avv = *(const float4*)(av + lane*4);
    unsigned short o[8];
#pragma unroll
    for (int e = 0; e < 8; ++e) {
      float4 wv4 = *(const float4*)(wp + (size_t)(g*8 + e)*256 + lane*4);
      float p = wv4.x*avv.x + wv4.y*avv.y + wv4.z*avv.z + wv4.w*avv.w;
#pragma unroll
      for (int off = 32; off; off >>= 1) p += __shfl_xor(p, off);
      o[e] = f2bf(p);
    }
    if (lane == 0) {
      ushort4 lo, hi;
      lo.x=o[0]; lo.y=o[1]; lo.z=o[2]; lo.w=o[3];
      hi.x=o[4]; hi.y=o[5]; hi.z=o[6]; hi.w=o[7];
      ushort4* dst = (ushort4*)(Wb + (size_t)(g*2432 + 2304 + c2)*8);
      dst[0] = lo; dst[1] = hi;
    }
  } else if (blockIdx.x < 4992) {
    // ---- xconv ----
    int idx = (blockIdx.x - 896)*256 + threadIdx.x;   // g*16384 + bn
    int bn = idx & 16383, g = idx >> 14;
    const float* xp = X + (size_t)bn*512 + g*8;
    ushort4 lo, hi;
    lo.x=f2bf(xp[0]); lo.y=f2bf(xp[1]); lo.z=f2bf(xp[2]); lo.w=f2bf(xp[3]);
    hi.x=f2bf(xp[4]); hi.y=f2bf(xp[5]); hi.z=f2bf(xp[6]); hi.w=f2bf(xp[7]);
    ushort4* dst = (ushort4*)(Xs + (size_t)idx*8);
    dst[0] = lo; dst[1] = hi;
  } else {
    // ---- bitpack (wave-per-row, 2 rows/wave) ----
    int gw = (blockIdx.x - 4992)*4 + (threadIdx.x >> 6);
    int lane = threadIdx.x & 63;
#pragma unroll
    for (int r = 0; r < 2; ++r) {
      int row = gw*2 + r;                  // bt*1024 + i, bt = b*3 + t
      int i = row & 1023, bt = row >> 10;
      int t = bt % 3, b = bt / 3;
      int sb = t*16 + b;
      const float* ap = adj + (size_t)row*1024 + lane;
      u64 myw = 0;
#pragma unroll
      for (int w = 0; w < 16; ++w) {
        u64 bal = __ballot(ap[w*64] > 0.0f);
        if (lane == w) myw = bal;
      }
      if (lane < 16) {
        mbA0[((size_t)sb*1024 + i)*16 + lane] = myw;
        mbT[((size_t)sb*16 + lane)*1024 + i] = myw;
      }
    }
  }
}

__global__ void k_boolmm(const u64* __restrict__ A, const u64* __restrict__ Bm,
                         u64* __restrict__ outA, u64* __restrict__ outT, int sbase)
{
  int tid = blockIdx.x*256 + threadIdx.x;   // 48*1024*16
  int w = tid & 15, i = (tid >> 4) & 1023, tb = tid >> 14;
  const u64* Ar = A + ((size_t)tb*1024 + i)*16;
  const u64* Bb = Bm + (size_t)tb*16384;
  u64 acc = 0;
  for (int ww = 0; ww < 16; ++ww) {
    u64 aw = Ar[ww];
    while (aw) {
      int kk = __builtin_ctzll(aw);
      aw &= aw - 1;
      acc |= Bb[((size_t)(ww*64 + kk))*16 + w];
    }
  }
  if (outA) outA[((size_t)tb*1024 + i)*16 + w] = acc;
  int t = tb >> 4, bq = tb & 15;
  outT[(((size_t)(sbase + t)*16 + bq)*16 + w)*1024 + i] = acc;
}

// ---------------- h = X@W GEMM (bf16 MFMA), fused f1L + G1/G2 epilogue -------
// R19 form (measured best): BK=64, two barriers per K-step, single buffer.

__global__ __launch_bounds__(256) void k_gemm_h(
    const unsigned short* __restrict__ Xs, const unsigned short* __restrict__ Wb,
    unsigned short* __restrict__ hsw, float* __restrict__ fbuf,
    float* __restrict__ G1p, float* __restrict__ G2p)
{
  __shared__ unsigned short Asl[8*132*8 + 8];
  __shared__ unsigned short Bsl[8*132*8 + 8];
  const int tid = threadIdx.x, lane = tid & 63, wid = tid >> 6;
  int vb = blockIdx.x;                       // XCD swizzle: same mt -> same XCD
  int xc = vb & 7, mrest = vb >> 3;
  int mt = xc + 8*(mrest/19), nt = mrest % 19;
  const int M0 = mt << 7, N0 = nt << 7;
  const int wr = (wid >> 1) << 6, wc = (wid & 1) << 6;
  const int me = lane & 15;
  f32x4 acc[4][4] = {};
  for (int ks64 = 0; ks64 < 8; ++ks64) {
    __syncthreads();
#pragma unroll
    for (int c = 0; c < 4; ++c) {
      int chunk = wid*4 + c, g = chunk >> 1, hh = chunk & 1;
      int ldsoff = (g*132 + hh*64)*8;
      const unsigned short* gpA = Xs + ((size_t)(ks64*8 + g)*16384 + (M0 + hh*64 + lane))*8;
      async_cp16(Asl + ldsoff, gpA);
      const unsigned short* gpB = Wb + ((size_t)(ks64*8 + g)*2432 + (N0 + hh*64 + lane))*8;
      async_cp16(Bsl + ldsoff, gpB);
    }
    __syncthreads();
#pragma unroll
    for (int ks32 = 0; ks32 < 2; ++ks32) {
      const int kg = ks32*4 + (lane >> 4);
      bf16x8 afr[4], bfr[4];
#pragma unroll
      for (int rb = 0; rb < 4; ++rb)
        afr[rb] = *(const bf16x8*)(Asl + (kg*132 + wr + rb*16 + me)*8);
#pragma unroll
      for (int cb = 0; cb < 4; ++cb)
        bfr[cb] = *(const bf16x8*)(Bsl + (kg*132 + wc + cb*16 + me)*8);
#pragma unroll
      for (int rb = 0; rb < 4; ++rb)
#pragma unroll
        for (int cb = 0; cb < 4; ++cb)
          acc[rb][cb] = __builtin_amdgcn_mfma_f32_16x16x32_bf16(afr[rb], bfr[cb], acc[rb][cb], 0, 0, 0);
    }
  }
  const int quad = lane >> 4;
#pragma unroll
  for (int rb = 0; rb < 4; ++rb) {
    int jbase = M0 + wr + rb*16 + quad*4;
    int bidx = jbase >> 10, jn = jbase & 1023;
#pragma unroll
    for (int cb = 0; cb < 4; ++cb) {
      int c = N0 + wc + cb*16 + me;
      f32x4 v = acc[rb][cb];
      if (c < 2304) {
        int s = c >> 8, f = c & 255;
        ushort4 pk;
        pk.x = f2bf(v[0]); pk.y = f2bf(v[1]); pk.z = f2bf(v[2]); pk.w = f2bf(v[3]);
        *(ushort4*)(hsw + (size_t)s*4194304 + (size_t)bidx*262144 + ((jn>>3)*256 + f)*8 + (jn&7)) = pk;
      } else if (c < 2322) {
        int c2 = c - 2304, s = c2 >> 1, wh = c2 & 1;
        f32x4 vL = v * L2E;                       // log2 domain
        if (wh == 0) {
          *(f32x4*)(fbuf + (size_t)s*16384 + jbase) = vL;   // f1L
        } else {
          f32x4 g1v, g2v;
#pragma unroll
          for (int k = 0; k < 4; ++k) {
            g1v[k] = fexp2(vL[k]);
            g2v[k] = fexp2(0.2f*vL[k]);
          }
          *(f32x4*)(G1p + (size_t)s*16384 + jbase) = g1v;
          *(f32x4*)(G2p + (size_t)s*16384 + jbase) = g2v;
        }
      }
    }
  }
}

// ---------------- per-row softmax denominators (exp-free, factorized) ----------
// Grid-stride, 8 rows per wave (grid 4608 x 256 = 18432 waves; 147456 rows).

__global__ __launch_bounds__(256) void k_rowl(
    const u64* __restrict__ mbT, const float* __restrict__ fbuf,
    const float* __restrict__ G1p, const float* __restrict__ G2p,
    float* __restrict__ rowR1, float* __restrict__ rowR2,
    float* __restrict__ rowRT, float* __restrict__ rowZr)
{
  int lane = threadIdx.x & 63;
  for (int gw = blockIdx.x*4 + (threadIdx.x >> 6); gw < 147456; gw += 18432) {
    int i = gw & 1023, sb = gw >> 10;
    int b = sb & 15, s = sb >> 4;

    const float* g1q = G1p + (size_t)s*16384 + b*1024 + lane*16;
    const float* g2q = G2p + (size_t)s*16384 + b*1024 + lane*16;
    float4 a0 = *(const float4*)(g1q);
    float4 a1 = *(const float4*)(g1q + 4);
    float4 a2 = *(const float4*)(g1q + 8);
    float4 a3 = *(const float4*)(g1q + 12);
    float4 c0 = *(const float4*)(g2q);
    float4 c1 = *(const float4*)(g2q + 4);
    float4 c2 = *(const float4*)(g2q + 8);
    float4 c3 = *(const float4*)(g2q + 12);
    float g1e[16] = {a0.x,a0.y,a0.z,a0.w, a1.x,a1.y,a1.z,a1.w,
                     a2.x,a2.y,a2.z,a2.w, a3.x,a3.y,a3.z,a3.w};
    float g2e[16] = {c0.x,c0.y,c0.z,c0.w, c1.x,c1.y,c1.z,c1.w,
                     c2.x,c2.y,c2.z,c2.w, c3.x,c3.y,c3.z,c3.w};

    u64 word = mbT[(size_t)sb*16384 + (size_t)(lane >> 2)*1024 + i];
    unsigned fld = (unsigned)(word >> ((lane & 3)*16)) & 0xFFFFu;   // 16 mask bits

    float f1i = fbuf[(size_t)s*16384 + b*1024 + i];
    float RT = fexp2(-f1i);

    float S1 = 0.0f, S2 = 0.0f;
#pragma unroll
    for (int e = 0; e < 16; ++e) {
      unsigned m32 = (unsigned)(((int)(fld << (31 - e))) >> 31);   // 0 or ~0
      float t1 = __uint_as_float(__float_as_uint(g1e[e]) & m32);
      float t2 = __uint_as_float(__float_as_uint(g2e[e]) & m32);
      bool c = (g1e[e] >= RT);
      S1 += c ? t1 : 0.0f;
      S2 += c ? 0.0f : t2;
    }
#pragma unroll
    for (int off = 32; off; off >>= 1) {
      S1 += __shfl_xor(S1, off);
      S2 += __shfl_xor(S2, off);
    }
    if (lane == 0) {
      float EF1 = fexp2(f1i);
      float EF2 = fexp2(0.2f*f1i);
      float l = __builtin_fmaf(EF1, S1, EF2*S2);
      float rinv = frcp(l);                 // inf when l==0 (empty row) -- harmless
      rowR1[gw] = EF1*rinv;
      rowR2[gw] = EF2*rinv;
      rowRT[gw] = RT;
      rowZr[gw] = (l == 0.0f) ? 0.0009765625f : 0.0f;   // 2^-10
    }
  }
}

// ---------------- fused attention GEMM: H = sum_t softmax(mask_t(e_t)) @ h_t --------
// R13 FINAL: exp-free 7-op P-gen, R8 loop structure, unpadded Bts (0 conflicts).

__global__ __launch_bounds__(256, 3) void k_attgemm(
    const unsigned short* __restrict__ hsw,
    const float* __restrict__ G1p, const float* __restrict__ G2p,
    const float* __restrict__ rowR1, const float* __restrict__ rowR2,
    const float* __restrict__ rowRT, const float* __restrict__ rowZr,
    const u64* __restrict__ mbT, float* __restrict__ H32)
{
  __shared__ unsigned short Bts[2*8192];      // 2 half-buffers, 16384B each (unpadded)
  const int tid = threadIdx.x, lane = tid & 63, wid = tid >> 6;
  const int me = lane & 15, quad = lane >> 4;
  int vb = blockIdx.x;
  int mt = vb / 48, g = vb % 48;              // g%8 constant across a group's 16 blocks
  int kl = g >> 4, b = g & 15;
  const int i0w = mt*64 + wid*16;
  const int ir0 = i0w + me;
  const unsigned short* hbase = hsw + (size_t)(kl*3)*4194304 + (size_t)b*262144;
  const float* g1b = G1p + (size_t)(kl*3)*16384 + b*1024;
  const float* g2b = G2p + (size_t)(kl*3)*16384 + b*1024;
  const float* R1b = rowR1 + ((kl*3)*16 + b)*1024;
  const float* R2b = rowR2 + ((kl*3)*16 + b)*1024;
  const float* RTb = rowRT + ((kl*3)*16 + b)*1024;
  const float* Zrb = rowZr + ((kl*3)*16 + b)*1024;
  const u64* mb = mbT + (size_t)((kl*3)*16 + b)*16384;   // t-stride 262144 u64

  float R1v, R2v, RTv;
  unsigned Zru;
  f32x4 acc[16] = {};

  // seed: stage iter 0 (t=0, st=0, ks=0) into buffer 0
  {
    const unsigned short* hstage = hbase + wid*2048;
    unsigned short* lb = Bts + wid*2048;
#pragma unroll
    for (int c = 0; c < 4; ++c)
      async_cp16(lb + c*512, hstage + c*512 + lane*8);
  }
  u64 mw = mb[ir0];
  u64 nm = 0;

  for (int it = 0; it < 96; ++it) {
    const int tt = it >> 5, kk = it & 1;
    const int st = (it >> 1) & 15;
    if ((it & 31) == 0) {                 // t boundary: per-row constants for this t
      R1v = R1b[tt*16384 + ir0];
      R2v = R2b[tt*16384 + ir0];
      RTv = RTb[tt*16384 + ir0];
      Zru = __float_as_uint(Zrb[tt*16384 + ir0]);
    }
    if (!kk && it) mw = nm;               // adopt prefetched mask

    __syncthreads();   // drains vmcnt: current half's loads issued one compute ago

    if (it + 1 < 96) {                    // stage next half into other buffer
      int nx = it + 1;
      int nt2 = nx >> 5, ns = (nx >> 1) & 15, nk = nx & 1;
      const unsigned short* hstage = hbase + (size_t)nt2*4194304 + ns*16384 + (nk*4 + wid)*2048;
      unsigned short* lb = Bts + nk*8192 + wid*2048;
#pragma unroll
      for (int c = 0; c < 4; ++c)
        async_cp16(lb + c*512, hstage + c*512 + lane*8);
    }
    if (kk && it + 1 < 96) {              // prefetch mask for next (t,st)
      int gid = (it + 1) >> 1;
      int nt2 = gid >> 4, ns = gid & 15;
      nm = mb[(size_t)nt2*262144 + ns*1024 + ir0];
    }

    // G1/G2 for this 32-k chunk (uniform-per-quad addresses -> L1 broadcast)
    const int joff = tt*16384 + st*64 + kk*32 + quad*8;
    float4 ga = *(const float4*)(g1b + joff);
    float4 gb4 = *(const float4*)(g1b + joff + 4);
    float4 ha = *(const float4*)(g2b + joff);
    float4 hb4 = *(const float4*)(g2b + joff + 4);
    float g1e[8] = {ga.x, ga.y, ga.z, ga.w, gb4.x, gb4.y, gb4.z, gb4.w};
    float g2e[8] = {ha.x, ha.y, ha.z, ha.w, hb4.x, hb4.y, hb4.z, hb4.w};

    const int kloc = kk*32 + quad*8;
    unsigned mby = (unsigned)((mw >> kloc) & 0xFFull);
    union { bf16x8 v; unsigned u[4]; } ua;
#pragma unroll
    for (int p = 0; p < 4; ++p) {
      float p0, p1;
      {
        const int e = 2*p;
        bool c = (g1e[e] >= RTv);
        float pu = (c ? g1e[e] : g2e[e]) * (c ? R1v : R2v);
        unsigned m32 = (unsigned)(((int)(mby << (31 - e))) >> 31);
        p0 = __uint_as_float((__float_as_uint(pu) & m32) | Zru);
      }
      {
        const int e = 2*p + 1;
        bool c = (g1e[e] >= RTv);
        float pu = (c ? g1e[e] : g2e[e]) * (c ? R1v : R2v);
        unsigned m32 = (unsigned)(((int)(mby << (31 - e))) >> 31);
        p1 = __uint_as_float((__float_as_uint(pu) & m32) | Zru);
      }
      ua.u[p] = pack_bf16x2(p0, p1);
    }
    const unsigned short* bbase = Bts + kk*8192 + quad*2048;
#pragma unroll
    for (int cb = 0; cb < 16; ++cb) {
      bf16x8 bf = *(const bf16x8*)(bbase + (cb*16 + me)*8);
      acc[cb] = __builtin_amdgcn_mfma_f32_16x16x32_bf16(ua.v, bf, acc[cb], 0, 0, 0);
    }
  }

  // epilogue: plain stores (each (kl,b,row,f) written exactly once)
  {
    int io = i0w + quad*4;
#pragma unroll
    for (int cb = 0; cb < 16; ++cb) {
      int f = cb*16 + me;
      float* hp = H32 + (((size_t)b*1024 + io)*3 + kl)*256 + f;
#pragma unroll
      for (int r = 0; r < 4; ++r)
        hp[(size_t)r*768] = acc[cb][r];
    }
  }
}

// ---------------- fused layer attention + combine (verified R17/R18) ----------------
// 512 blocks x 384 thr (6 waves). Score phase: rows [blk*96, +96) (= 32 bn x 3 kl),
// s = tanh(H@Ww+bw)@Wc -> svL in LDS. Barrier. Combine phase: softmax over the 3
// layer scores per bn, weighted sum of H32 rows (L2-hot re-read), write out.

__global__ __launch_bounds__(384) void k_scorecomb(
    const float* __restrict__ H32, const float* __restrict__ Ww,
    const float* __restrict__ bwv, const float* __restrict__ Wcv,
    float* __restrict__ out)
{
  __shared__ unsigned short Bs[8*7*64*8];   // 57344 B
  __shared__ float bwL[128], WcL[128];
  __shared__ float svL[96];
  const int tid = threadIdx.x, lane = tid & 63, wid = tid >> 6;   // wid 0..5
  const int me = lane & 15, quad = lane >> 4;
  for (int idx = tid; idx < 3584; idx += 384) {
    int kk = idx / 448, rem = idx % 448;
    int cb = rem >> 6, l = rem & 63;
    int n = cb*16 + (l & 15);
    int kbase = kk*32 + (l >> 4)*8;
    ushort4 lo, hi;
    if (n < 100) {
      const float* wp = Ww + (size_t)kbase*100 + n;
      lo.x = f2bf(wp[0]);   lo.y = f2bf(wp[100]); lo.z = f2bf(wp[200]); lo.w = f2bf(wp[300]);
      hi.x = f2bf(wp[400]); hi.y = f2bf(wp[500]); hi.z = f2bf(wp[600]); hi.w = f2bf(wp[700]);
    } else {
      lo.x=lo.y=lo.z=lo.w=0; hi.x=hi.y=hi.z=hi.w=0;
    }
    ushort4* dst = (ushort4*)(Bs + (size_t)idx*8);
    dst[0] = lo; dst[1] = hi;
  }
  if (tid < 128) {
    bwL[tid] = (tid < 100) ? bwv[tid] : 0.0f;
    WcL[tid] = (tid < 100) ? Wcv[tid] : 0.0f;
  }
  __syncthreads();

  // ---- score phase: 96 rows (rows are (bn*3 + kl) indices into H32) ----
  const int row0 = blockIdx.x*96 + wid*16;
  const float* Arow = H32 + (size_t)(row0 + me)*256;
  f32x4 acc[7] = {};
#pragma unroll
  for (int kk = 0; kk < 8; ++kk) {
    const float* ap = Arow + kk*32 + quad*8;
    float4 a0 = *(const float4*)(ap);
    float4 a1 = *(const float4*)(ap + 4);
    union { bf16x8 v; unsigned u[4]; } ua;
    ua.u[0] = pack_bf16x2(a0.x, a0.y);
    ua.u[1] = pack_bf16x2(a0.z, a0.w);
    ua.u[2] = pack_bf16x2(a1.x, a1.y);
    ua.u[3] = pack_bf16x2(a1.z, a1.w);
#pragma unroll
    for (int cb = 0; cb < 7; ++cb) {
      bf16x8 bf = *(const bf16x8*)(Bs + ((size_t)(kk*7 + cb)*64 + lane)*8);
      acc[cb] = __builtin_amdgcn_mfma_f32_16x16x32_bf16(ua.v, bf, acc[cb], 0, 0, 0);
    }
  }
#pragma unroll
  for (int r = 0; r < 4; ++r) {
    float contrib = 0.0f;
#pragma unroll
    for (int cb = 0; cb < 7; ++cb) {
      int col = cb*16 + me;
      contrib += tanh_fast(acc[cb][r] + bwL[col]) * WcL[col];
    }
    contrib += __shfl_xor(contrib, 1);
    contrib += __shfl_xor(contrib, 2);
    contrib += __shfl_xor(contrib, 4);
    contrib += __shfl_xor(contrib, 8);
    if (me == 0) svL[wid*16 + quad*4 + r] = contrib;
  }
  __syncthreads();

  // ---- combine phase: 32 bn, H32 rows re-read (L2-hot) ----
  const int bn0 = blockIdx.x*32;
  for (int idx = tid; idx < 2048; idx += 384) {
    int fq = idx & 63, bl = idx >> 6;       // bl in [0,32)
    int bn = bn0 + bl;
    float s0 = svL[bl*3], s1 = svL[bl*3+1], s2 = svL[bl*3+2];
    float mm = fmaxf(s0, fmaxf(s1, s2));
    float e0 = fexp2((s0-mm)*L2E), e1 = fexp2((s1-mm)*L2E), e2 = fexp2((s2-mm)*L2E);
    float inv = frcp(e0 + e1 + e2);
    const f32x4* h0 = (const f32x4*)(H32 + (size_t)bn*768) + fq;
    const f32x4* h1 = (const f32x4*)(H32 + (size_t)bn*768 + 256) + fq;
    const f32x4* h2 = (const f32x4*)(H32 + (size_t)bn*768 + 512) + fq;
    f32x4 r = (e0*(*h0) + e1*(*h1) + e2*(*h2))*inv;
    *((f32x4*)out + (size_t)bn*64 + fq) = r;
  }
}

// ---------------- launcher ----------------

extern "C" void kernel_launch(void* const* d_in, const int* in_sizes, int n_in,
                              void* d_out, int out_size, void* d_ws, size_t ws_size,
                              hipStream_t stream) {
  const float* adj = (const float*)d_in[0];
  const float* X   = (const float*)d_in[1];
  const float* W   = (const float*)d_in[2];
  const float* a1  = (const float*)d_in[3];
  const float* a2  = (const float*)d_in[4];
  const float* Ww  = (const float*)d_in[5];
  const float* bw  = (const float*)d_in[6];
  const float* Wc  = (const float*)d_in[7];
  float* out = (float*)d_out;
  char* ws = (char*)d_ws;

  unsigned short* Xs  = (unsigned short*)(ws + 0);
  unsigned short* Wb  = (unsigned short*)(ws + 16777216);
  float* H32          = (float*)(ws + 0);                // reuses Xs/Wb region
  unsigned short* hsw = (unsigned short*)(ws + 50331648);
  u64* mbA            = (u64*)(ws + 125829120);
  float* rowR1        = (float*)(ws + 125829120);        // mbA lvl0, dead after boolmm-2
  float* rowR2        = (float*)(ws + 126418944);
  float* rowRT        = (float*)(ws + 127008768);
  float* rowZr        = (float*)(ws + 127598592);
  u64* mbT            = (u64*)(ws + 138412032);
  float* fbuf         = (float*)(ws + 157286400);        // f1L
  float* G1p          = (float*)(ws + 158466048);
  float* G2p          = (float*)(ws + 159055872);

  // prep: build_wb (parallel dots) | xconv | bitpack -- one homogeneous launch
  k_prep<<<11136, 256, 0, stream>>>(W, a1, a2, Wb, X, Xs, adj, mbA, mbT);
  k_boolmm<<<3072, 256, 0, stream>>>(mbA, mbA, mbA + 786432, mbT, 3);
  // adj^3 = adj * adj^2 (sparse A side: ~10 gathers/word vs ~97 for adj^2 * adj)
  k_boolmm<<<3072, 256, 0, stream>>>(mbA, mbA + 786432, (u64*)nullptr, mbT, 6);
  k_gemm_h<<<2432, 256, 0, stream>>>(Xs, Wb, hsw, fbuf, G1p, G2p);
  k_rowl<<<4608, 256, 0, stream>>>(mbT, fbuf, G1p, G2p, rowR1, rowR2, rowRT, rowZr);
  k_attgemm<<<768, 256, 0, stream>>>(hsw, G1p, G2p, rowR1, rowR2, rowRT, rowZr, mbT, H32);
  k_scorecomb<<<512, 384, 0, stream>>>(H32, Ww, bw, Wc, out);
}